// Round 7
// baseline (834.179 us; speedup 1.0000x reference)
//
#include <hip/hip_runtime.h>

#define NN 512
#define DD 256

typedef float f32x4 __attribute__((ext_vector_type(4)));
typedef short s16x8 __attribute__((ext_vector_type(8)));

__device__ __forceinline__ unsigned short f2bf(float f) {
    unsigned u = __float_as_uint(f);
    u += 0x7fffu + ((u >> 16) & 1u);   // round-to-nearest-even
    return (unsigned short)(u >> 16);
}

__device__ __forceinline__ s16x8 pack_bf(const f32x4 v0, const f32x4 v1) {
    s16x8 a;
    a[0] = (short)f2bf(v0[0]); a[1] = (short)f2bf(v0[1]);
    a[2] = (short)f2bf(v0[2]); a[3] = (short)f2bf(v0[3]);
    a[4] = (short)f2bf(v1[0]); a[5] = (short)f2bf(v1[1]);
    a[6] = (short)f2bf(v1[2]); a[7] = (short)f2bf(v1[3]);
    return a;
}

// ---------------------------------------------------------------------------
// K1: hb = h@W1.T + t_bias, hW2 = h@W2.T, hW4 = h@W4.T, w3b = bf16(W3).
// ---------------------------------------------------------------------------
__global__ __launch_bounds__(256) void k1_pre(
    const float* __restrict__ h,  const float* __restrict__ W1,
    const float* __restrict__ W2, const float* __restrict__ W4,
    const float* __restrict__ t_emb, const float* __restrict__ W_t,
    const float* __restrict__ W3,
    float* __restrict__ hb, float* __restrict__ hW2, float* __restrict__ hW4,
    unsigned short* __restrict__ w3b)
{
    __shared__ float xs[8][DD];
    __shared__ float st[DD];
    const int b = blockIdx.x;
    const int t = threadIdx.x;
    if (b < 64) {
        #pragma unroll
        for (int r = 0; r < 8; ++r) xs[r][t] = h[(size_t)(b * 8 + r) * DD + t];
        st[t] = t_emb[t];
        __syncthreads();
        float a1[8], a2[8], a4[8];
        #pragma unroll
        for (int r = 0; r < 8; ++r) { a1[r] = 0.f; a2[r] = 0.f; a4[r] = 0.f; }
        float tb = 0.f;
        for (int d = 0; d < DD; ++d) {
            const float w1 = W1[(size_t)t * DD + d];
            const float w2 = W2[(size_t)t * DD + d];
            const float w4 = W4[(size_t)t * DD + d];
            tb = fmaf(st[d], W_t[(size_t)t * DD + d], tb);
            #pragma unroll
            for (int r = 0; r < 8; ++r) {
                const float x = xs[r][d];
                a1[r] = fmaf(x, w1, a1[r]);
                a2[r] = fmaf(x, w2, a2[r]);
                a4[r] = fmaf(x, w4, a4[r]);
            }
        }
        #pragma unroll
        for (int r = 0; r < 8; ++r) {
            const size_t o = (size_t)(b * 8 + r) * DD + t;
            hb[o] = a1[r] + tb; hW2[o] = a2[r]; hW4[o] = a4[r];
        }
    } else {
        for (int c = t; c < DD * DD / 4; c += 256) {
            const f32x4 v = *reinterpret_cast<const f32x4*>(W3 + (size_t)c * 4);
            const unsigned lo = ((unsigned)f2bf(v[1]) << 16) | f2bf(v[0]);
            const unsigned hi = ((unsigned)f2bf(v[3]) << 16) | f2bf(v[2]);
            *reinterpret_cast<uint2*>(w3b + (size_t)c * 4) = make_uint2(lo, hi);
        }
    }
}

// ---------------------------------------------------------------------------
// K2 (fully fused): block = one full i (512 j-rows), 512 threads = 8 waves.
// B = bf16(W3) staged ONCE into LDS, swizzled (chunk ^= col&15) -> every
// ds_read_b128 hits the 8-bank-cycle floor. Waves are m-split (16 rows each,
// 4 tiles), barrier-free between stage and final reduce:
//   A per-lane from global (32 KB/wave in flight), cvt->bf16, 8 K-steps x
//   16 n-frags MFMA, wave-local LN/relu/store/gate/exp (R3-verified layout).
// Tail: exact softmax partials (no-max exp, R6-validated) -> weighted ->
// W5 matvec + h-LN + residual. k3/k4 eliminated.
// ---------------------------------------------------------------------------
__global__ __launch_bounds__(512) void k2_fused(
    const float* __restrict__ e,
    const unsigned short* __restrict__ w3b,
    const float* __restrict__ hb, const float* __restrict__ hW2,
    const float* __restrict__ gate_w, const float* __restrict__ gate_b,
    const float* __restrict__ ln_e_w, const float* __restrict__ ln_e_b,
    const float* __restrict__ h, const float* __restrict__ hW4,
    const float* __restrict__ W5,
    const float* __restrict__ ln_h_w, const float* __restrict__ ln_h_b,
    float* __restrict__ out_h, float* __restrict__ out_e)
{
    __shared__ __align__(16) unsigned char sB[DD * 512];   // 128 KiB bf16 [col][k], swizzled
    __shared__ float s_hb[DD], s_lnw[DD], s_lnb[DD], s_gw[DD];
    __shared__ float s_pw[8][DD];
    __shared__ float s_zw[8];
    __shared__ float s_wgt[DD];
    __shared__ float s_red[DD];

    const int i = blockIdx.x;
    const int tid = threadIdx.x;
    const int w = tid >> 6;
    const int l = tid & 63;
    const int l15 = l & 15;
    const int lg = l >> 4;                    // 0..3

    // ---- stage B swizzled: chunk kc of col stored at slot kc^(col&15) ----
    #pragma unroll
    for (int s = 0; s < 16; ++s) {
        const int c = s * 512 + tid;          // 16B chunk id, 0..8191
        const int col = c >> 5;
        const int kc = c & 31;
        const s16x8 bv = *reinterpret_cast<const s16x8*>(w3b + (size_t)c * 8);
        *reinterpret_cast<s16x8*>(sB + col * 512 + ((kc ^ (col & 15)) << 4)) = bv;
    }
    if (tid < DD) {
        s_hb[tid]  = hb[(size_t)i * DD + tid];
        s_lnw[tid] = ln_e_w[tid];
        s_lnb[tid] = ln_e_b[tid];
        s_gw[tid]  = gate_w[tid];
    }
    __syncthreads();

    const float gb = gate_b[0];
    float p[16];
    #pragma unroll
    for (int n = 0; n < 16; ++n) p[n] = 0.f;
    float z_acc = 0.f;

    for (int t = 0; t < 4; ++t) {
        const int j0 = t * 128 + w * 16;      // rows j0..j0+15 of this i
        const float* ap = e + (size_t)(i * NN + j0 + l15) * DD + lg * 8;

        // ---- A: per-lane global loads (16 x dwordx4 = 32 KB/wave in flight) ----
        f32x4 af[16];
        #pragma unroll
        for (int kk = 0; kk < 8; ++kk) {
            af[2 * kk]     = *reinterpret_cast<const f32x4*>(ap + kk * 32);
            af[2 * kk + 1] = *reinterpret_cast<const f32x4*>(ap + kk * 32 + 4);
        }
        s16x8 abf[8];
        #pragma unroll
        for (int kk = 0; kk < 8; ++kk) abf[kk] = pack_bf(af[2 * kk], af[2 * kk + 1]);

        f32x4 acc[16];
        #pragma unroll
        for (int n = 0; n < 16; ++n) acc[n] = (f32x4){0.f, 0.f, 0.f, 0.f};

        #pragma unroll
        for (int kk = 0; kk < 8; ++kk) {
            const int ksl = kk * 4 + lg;      // 16B chunk index within row
            #pragma unroll
            for (int n = 0; n < 16; ++n) {
                const int col = n * 16 + l15;
                const s16x8 bfr = *reinterpret_cast<const s16x8*>(
                    sB + col * 512 + ((ksl ^ l15) << 4));
                acc[n] = __builtin_amdgcn_mfma_f32_16x16x32_bf16(abf[kk], bfr, acc[n], 0, 0, 0);
            }
        }

        // ---- wave-local epilogue: rows j0+lg*4+q, cols n*16+l15 ----
        #pragma unroll
        for (int q = 0; q < 4; ++q) {
            const int jrow = j0 + lg * 4 + q;
            const float* h2p = hW2 + (size_t)jrow * DD + l15;
            float s1 = 0.f, s2 = 0.f;
            #pragma unroll
            for (int n = 0; n < 16; ++n) {
                const float v = acc[n][q] + s_hb[n * 16 + l15] + h2p[n * 16];
                acc[n][q] = v;
                s1 += v;
                s2 = fmaf(v, v, s2);
            }
            #pragma unroll
            for (int s = 1; s < 16; s <<= 1) {
                s1 += __shfl_xor(s1, s, 64);
                s2 += __shfl_xor(s2, s, 64);
            }
            const float mu = s1 * (1.f / 256.f);
            const float rs = rsqrtf(s2 * (1.f / 256.f) - mu * mu + 1e-5f);

            float gl = 0.f;
            const size_t rowg = (size_t)(i * NN + jrow) * DD;
            #pragma unroll
            for (int n = 0; n < 16; ++n) {
                const int col = n * 16 + l15;
                float v = (acc[n][q] - mu) * rs * s_lnw[col] + s_lnb[col];
                v = fmaxf(v, 0.f);
                out_e[rowg + col] = v;
                acc[n][q] = v;
                gl = fmaf(v, s_gw[col], gl);
            }
            #pragma unroll
            for (int s = 1; s < 16; s <<= 1) gl += __shfl_xor(gl, s, 64);
            const float ex = __expf(gl + gb);
            z_acc += ex;
            #pragma unroll
            for (int n = 0; n < 16; ++n) p[n] = fmaf(ex, acc[n][q], p[n]);
        }
    }

    // ---- reduce p,z over lg; write per-wave partials ----
    #pragma unroll
    for (int n = 0; n < 16; ++n) {
        p[n] += __shfl_xor(p[n], 16, 64);
        p[n] += __shfl_xor(p[n], 32, 64);
    }
    z_acc += __shfl_xor(z_acc, 16, 64);
    z_acc += __shfl_xor(z_acc, 32, 64);
    if (lg == 0) {
        #pragma unroll
        for (int n = 0; n < 16; ++n) s_pw[w][n * 16 + l15] = p[n];
    }
    if (l == 0) s_zw[w] = z_acc;
    __syncthreads();

    // ---- weighted[i,:] = sum_w p / sum_w z ----
    float hp = 0.f;
    if (tid < DD) {
        float sp = 0.f, zz = 0.f;
        #pragma unroll
        for (int w8 = 0; w8 < 8; ++w8) { sp += s_pw[w8][tid]; zz += s_zw[w8]; }
        s_wgt[tid] = sp / zz;
    }
    __syncthreads();

    // ---- h-path: hp = hW4[i] + weighted@W5.T ----
    if (tid < DD) {
        const float* w5r = W5 + (size_t)tid * DD;
        float a = 0.f;
        for (int d = 0; d < DD; ++d) a = fmaf(s_wgt[d], w5r[d], a);
        hp = hW4[(size_t)i * DD + tid] + a;
        s_red[tid] = hp;
    }
    __syncthreads();
    for (int s = 128; s > 0; s >>= 1) {
        if (tid < s) s_red[tid] += s_red[tid + s];
        __syncthreads();
    }
    const float mu_h = s_red[0] * (1.f / 256.f);
    __syncthreads();
    if (tid < DD) { const float d0 = hp - mu_h; s_red[tid] = d0 * d0; }
    __syncthreads();
    for (int s = 128; s > 0; s >>= 1) {
        if (tid < s) s_red[tid] += s_red[tid + s];
        __syncthreads();
    }
    if (tid < DD) {
        const float rs = rsqrtf(s_red[0] * (1.f / 256.f) + 1e-5f);
        float v = (hp - mu_h) * rs * ln_h_w[tid] + ln_h_b[tid];
        v = fmaxf(v, 0.f);
        out_h[(size_t)i * DD + tid] = h[(size_t)i * DD + tid] + v;
    }
}

// ---------------------------------------------------------------------------
extern "C" void kernel_launch(void* const* d_in, const int* in_sizes, int n_in,
                              void* d_out, int out_size, void* d_ws, size_t ws_size,
                              hipStream_t stream)
{
    const float* h      = (const float*)d_in[0];
    const float* e      = (const float*)d_in[1];
    const float* t_emb  = (const float*)d_in[2];
    const float* W1     = (const float*)d_in[3];
    const float* W2     = (const float*)d_in[4];
    const float* W3     = (const float*)d_in[5];
    const float* W_t    = (const float*)d_in[6];
    const float* W4     = (const float*)d_in[7];
    const float* W5     = (const float*)d_in[8];
    const float* gate_w = (const float*)d_in[9];
    const float* gate_b = (const float*)d_in[10];
    const float* ln_e_w = (const float*)d_in[11];
    const float* ln_e_b = (const float*)d_in[12];
    const float* ln_h_w = (const float*)d_in[13];
    const float* ln_h_b = (const float*)d_in[14];

    float* out_h = (float*)d_out;
    float* out_e = out_h + NN * DD;

    // workspace layout (~1.6 MiB)
    float* wsf = (float*)d_ws;
    float* hb  = wsf;                         // 131072 (hW1 + t_bias)
    float* hW2 = hb + NN * DD;                // 131072
    float* hW4 = hW2 + NN * DD;               // 131072
    unsigned short* w3b = (unsigned short*)(hW4 + NN * DD);  // 65536 ushort

    k1_pre<<<65, 256, 0, stream>>>(h, W1, W2, W4, t_emb, W_t, W3,
                                   hb, hW2, hW4, w3b);
    k2_fused<<<512, 512, 0, stream>>>(e, w3b, hb, hW2, gate_w, gate_b,
                                      ln_e_w, ln_e_b, h, hW4, W5,
                                      ln_h_w, ln_h_b, out_h, out_e);
}

// Round 8
// 274.920 us; speedup vs baseline: 3.0343x; 3.0343x over previous
//
#include <hip/hip_runtime.h>

#define NN 512
#define DD 256

typedef float f32x4 __attribute__((ext_vector_type(4)));
typedef short s16x8 __attribute__((ext_vector_type(8)));

__device__ __forceinline__ unsigned short f2bf(float f) {
    unsigned u = __float_as_uint(f);
    u += 0x7fffu + ((u >> 16) & 1u);   // round-to-nearest-even
    return (unsigned short)(u >> 16);
}
__device__ __forceinline__ float bf2f(unsigned short s) {
    return __uint_as_float(((unsigned)s) << 16);
}

// ---------------------------------------------------------------------------
// K1: hb = h@W1.T + t_bias, hW2 = h@W2.T, hW4 = h@W4.T, w3b = bf16(W3),
//     zero the softmax accumulators (wacc, zacc).
// ---------------------------------------------------------------------------
__global__ __launch_bounds__(256) void k1_pre(
    const float* __restrict__ h,  const float* __restrict__ W1,
    const float* __restrict__ W2, const float* __restrict__ W4,
    const float* __restrict__ t_emb, const float* __restrict__ W_t,
    const float* __restrict__ W3,
    float* __restrict__ hb, float* __restrict__ hW2, float* __restrict__ hW4,
    unsigned short* __restrict__ w3b,
    float* __restrict__ wacc, float* __restrict__ zacc)
{
    __shared__ float xs[8][DD];
    __shared__ float st[DD];
    const int b = blockIdx.x;
    const int t = threadIdx.x;
    if (b < 64) {
        #pragma unroll
        for (int r = 0; r < 8; ++r) xs[r][t] = h[(size_t)(b * 8 + r) * DD + t];
        st[t] = t_emb[t];
        __syncthreads();
        float a1[8], a2[8], a4[8];
        #pragma unroll
        for (int r = 0; r < 8; ++r) { a1[r] = 0.f; a2[r] = 0.f; a4[r] = 0.f; }
        float tb = 0.f;
        for (int d = 0; d < DD; ++d) {
            const float w1 = W1[(size_t)t * DD + d];
            const float w2 = W2[(size_t)t * DD + d];
            const float w4 = W4[(size_t)t * DD + d];
            tb = fmaf(st[d], W_t[(size_t)t * DD + d], tb);
            #pragma unroll
            for (int r = 0; r < 8; ++r) {
                const float x = xs[r][d];
                a1[r] = fmaf(x, w1, a1[r]);
                a2[r] = fmaf(x, w2, a2[r]);
                a4[r] = fmaf(x, w4, a4[r]);
            }
        }
        #pragma unroll
        for (int r = 0; r < 8; ++r) {
            const size_t o = (size_t)(b * 8 + r) * DD + t;
            hb[o] = a1[r] + tb; hW2[o] = a2[r]; hW4[o] = a4[r];
        }
    } else if (b == 64) {
        for (int c = t; c < DD * DD / 4; c += 256) {
            const f32x4 v = *reinterpret_cast<const f32x4*>(W3 + (size_t)c * 4);
            const unsigned lo = ((unsigned)f2bf(v[1]) << 16) | f2bf(v[0]);
            const unsigned hi = ((unsigned)f2bf(v[3]) << 16) | f2bf(v[2]);
            *reinterpret_cast<uint2*>(w3b + (size_t)c * 4) = make_uint2(lo, hi);
        }
    } else {
        const f32x4 zero = (f32x4){0.f, 0.f, 0.f, 0.f};
        for (int c = t; c < NN * DD / 4; c += 256)
            *reinterpret_cast<f32x4*>(wacc + (size_t)c * 4) = zero;
        if (t < 256) { zacc[t] = 0.f; zacc[t + 256] = 0.f; }
    }
}

// ---------------------------------------------------------------------------
// K2: pre = e@W3.T + hb[i] + hW2[j]; e_new = relu(LN(pre)); fused no-max
// softmax partials -> atomicAdd into wacc[i,:], zacc[i].
// Block = 32 rows, 4 n-split waves (cols w*64..+64), acc[2][4] (32 AGPR).
// Fixes vs R4: depth-4 B-register prefetch (L2-latency cover); hW2-slab
// (bf16) + hb + LN/gate tables staged to LDS in the prologue burst; serial
// tid<32 phases replaced by redundant broadcast reads; k3 fused away.
// ---------------------------------------------------------------------------
__global__ __launch_bounds__(256) void k2_big(
    const float* __restrict__ e,
    const unsigned short* __restrict__ w3b,
    const float* __restrict__ hb, const float* __restrict__ hW2,
    const float* __restrict__ gate_w, const float* __restrict__ gate_b,
    const float* __restrict__ ln_e_w, const float* __restrict__ ln_e_b,
    float* __restrict__ out_e,
    float* __restrict__ wacc, float* __restrict__ zacc)
{
    const int b = blockIdx.x;
    const int row_base = b * 32;              // flat row = i*512 + j
    const int i = row_base >> 9;
    const int j0 = row_base & 511;
    const int tid = threadIdx.x;
    const int w = tid >> 6;
    const int l = tid & 63;
    const int l15 = l & 15;
    const int lg = l >> 4;                    // 0..3

    __shared__ __align__(16) unsigned char sA[32 * 256 * 2];    // 16 KiB bf16, swizzled
    __shared__ __align__(16) unsigned char sH2[32 * 256 * 2];   // 16 KiB bf16, swizzled
    __shared__ unsigned short s_hbu[DD];
    __shared__ float s_lnw[DD], s_lnb[DD], s_gw[DD];
    __shared__ float s_part[32][4][2];
    __shared__ float s_glog[32][4];

    // ---- prologue: A-tile loads ----
    const float* esrc = e + (size_t)row_base * DD;
    f32x4 av[8];
    #pragma unroll
    for (int s = 0; s < 8; ++s)
        av[s] = *reinterpret_cast<const f32x4*>(esrc + (size_t)(s * 256 + tid) * 4);

    // ---- B: all 4 K-slot fragments (depth-4 prefetch base) ----
    const unsigned short* bp = w3b + (size_t)(w * 64 + l15) * DD + lg * 8;
    s16x8 bb[4][4];
    #pragma unroll
    for (int kk = 0; kk < 4; ++kk)
        #pragma unroll
        for (int n = 0; n < 4; ++n)
            bb[kk][n] = *reinterpret_cast<const s16x8*>(bp + (size_t)n * 16 * DD + kk * 32);

    const float gb = gate_b[0];
    // small tables -> LDS
    s_lnw[tid] = ln_e_w[tid];
    s_lnb[tid] = ln_e_b[tid];
    s_gw[tid]  = gate_w[tid];
    s_hbu[tid] = f2bf(hb[(size_t)i * DD + tid]);

    // ---- A cvt -> swizzled LDS (av dies) ----
    #pragma unroll
    for (int s = 0; s < 8; ++s) {
        const int flat = s * 256 + tid;
        const int r = flat >> 6;
        const int c4 = (flat & 63) * 4;
        const f32x4 v = av[s];
        const unsigned lo = ((unsigned)f2bf(v[1]) << 16) | f2bf(v[0]);
        const unsigned hi = ((unsigned)f2bf(v[3]) << 16) | f2bf(v[2]);
        const unsigned byte = ((unsigned)(r * 512 + c4 * 2)) ^ ((unsigned)(r & 7) << 4);
        *reinterpret_cast<uint2*>(sA + byte) = make_uint2(lo, hi);
    }

    // ---- hW2 slab loads + cvt -> swizzled bf16 LDS ----
    {
        const float* h2src = hW2 + (size_t)j0 * DD;
        f32x4 hv[8];
        #pragma unroll
        for (int s = 0; s < 8; ++s)
            hv[s] = *reinterpret_cast<const f32x4*>(h2src + (size_t)(s * 256 + tid) * 4);
        #pragma unroll
        for (int s = 0; s < 8; ++s) {
            const int flat = s * 256 + tid;
            const int r = flat >> 6;
            const int c4 = (flat & 63) * 4;
            const f32x4 v = hv[s];
            const unsigned lo = ((unsigned)f2bf(v[1]) << 16) | f2bf(v[0]);
            const unsigned hi = ((unsigned)f2bf(v[3]) << 16) | f2bf(v[2]);
            const unsigned byte = ((unsigned)(r * 512 + c4 * 2)) ^ ((unsigned)(r & 7) << 4);
            *reinterpret_cast<uint2*>(sH2 + byte) = make_uint2(lo, hi);
        }
    }
    __syncthreads();

    // ---- MFMA K-loop: A from LDS, B regs, distance-4 prefetch ----
    f32x4 acc[2][4];
    #pragma unroll
    for (int m = 0; m < 2; ++m)
        #pragma unroll
        for (int n = 0; n < 4; ++n)
            acc[m][n] = (f32x4){0.f, 0.f, 0.f, 0.f};

    const unsigned aswz = ((unsigned)(l15 & 7) << 4);
    #pragma unroll
    for (int kk = 0; kk < 8; ++kk) {
        s16x8 afr[2];
        #pragma unroll
        for (int m = 0; m < 2; ++m) {
            const unsigned byte = ((unsigned)((m * 16 + l15) * 512 + kk * 64 + lg * 16)) ^ aswz;
            afr[m] = *reinterpret_cast<const s16x8*>(sA + byte);
        }
        #pragma unroll
        for (int n = 0; n < 4; ++n)
            #pragma unroll
            for (int m = 0; m < 2; ++m)
                acc[m][n] = __builtin_amdgcn_mfma_f32_16x16x32_bf16(afr[m], bb[kk & 3][n], acc[m][n], 0, 0, 0);
        if (kk < 4) {   // prefetch kk+4 into the slot just consumed
            #pragma unroll
            for (int n = 0; n < 4; ++n)
                bb[kk & 3][n] = *reinterpret_cast<const s16x8*>(bp + (size_t)n * 16 * DD + (kk + 4) * 32);
        }
    }

    // ---- epilogue A: biases (from LDS) + LN partial sums ----
    float hbn[4];
    #pragma unroll
    for (int n = 0; n < 4; ++n) hbn[n] = bf2f(s_hbu[w * 64 + n * 16 + l15]);

    #pragma unroll
    for (int m = 0; m < 2; ++m) {
        #pragma unroll
        for (int q = 0; q < 4; ++q) {
            const int r = m * 16 + lg * 4 + q;
            const unsigned rsw = ((unsigned)(r & 7) << 4);
            float s1 = 0.f, s2 = 0.f;
            #pragma unroll
            for (int n = 0; n < 4; ++n) {
                const int c = w * 64 + n * 16 + l15;
                const unsigned short h2u = *reinterpret_cast<const unsigned short*>(
                    sH2 + (((unsigned)(r * 512 + c * 2)) ^ rsw));
                const float v = acc[m][n][q] + hbn[n] + bf2f(h2u);
                acc[m][n][q] = v;
                s1 += v;
                s2 = fmaf(v, v, s2);
            }
            #pragma unroll
            for (int s = 1; s < 16; s <<= 1) {
                s1 += __shfl_xor(s1, s, 64);
                s2 += __shfl_xor(s2, s, 64);
            }
            if (l15 == 0) { s_part[r][w][0] = s1; s_part[r][w][1] = s2; }
        }
    }
    __syncthreads();

    // ---- epilogue B: redundant stats, normalize, relu, store, gate ----
    #pragma unroll
    for (int m = 0; m < 2; ++m) {
        #pragma unroll
        for (int q = 0; q < 4; ++q) {
            const int r = m * 16 + lg * 4 + q;
            float S1 = 0.f, S2 = 0.f;
            #pragma unroll
            for (int ww = 0; ww < 4; ++ww) { S1 += s_part[r][ww][0]; S2 += s_part[r][ww][1]; }
            const float mu = S1 * (1.f / 256.f);
            const float rs = rsqrtf(S2 * (1.f / 256.f) - mu * mu + 1e-5f);
            const size_t rowg = (size_t)(row_base + r);
            float gl = 0.f;
            #pragma unroll
            for (int n = 0; n < 4; ++n) {
                const int c = w * 64 + n * 16 + l15;
                float v = (acc[m][n][q] - mu) * rs * s_lnw[c] + s_lnb[c];
                v = fmaxf(v, 0.f);
                acc[m][n][q] = v;
                out_e[rowg * DD + c] = v;
                gl = fmaf(v, s_gw[c], gl);
            }
            #pragma unroll
            for (int s = 1; s < 16; s <<= 1) gl += __shfl_xor(gl, s, 64);
            if (l15 == 0) s_glog[r][w] = gl;
        }
    }
    __syncthreads();

    // ---- fused no-max softmax partials ----
    float p[4] = {0.f, 0.f, 0.f, 0.f};
    float zl = 0.f;
    #pragma unroll
    for (int m = 0; m < 2; ++m) {
        #pragma unroll
        for (int q = 0; q < 4; ++q) {
            const int r = m * 16 + lg * 4 + q;
            const float lv = gb + s_glog[r][0] + s_glog[r][1] + s_glog[r][2] + s_glog[r][3];
            const float ex = __expf(lv);
            zl += ex;
            #pragma unroll
            for (int n = 0; n < 4; ++n) p[n] = fmaf(ex, acc[m][n][q], p[n]);
        }
    }
    #pragma unroll
    for (int n = 0; n < 4; ++n) {
        p[n] += __shfl_xor(p[n], 16, 64);
        p[n] += __shfl_xor(p[n], 32, 64);
    }
    zl += __shfl_xor(zl, 16, 64);
    zl += __shfl_xor(zl, 32, 64);
    if (lg == 0) {
        #pragma unroll
        for (int n = 0; n < 4; ++n)
            atomicAdd(&wacc[(size_t)i * DD + w * 64 + n * 16 + l15], p[n]);
    }
    if (w == 0 && l == 0) atomicAdd(&zacc[i], zl);
}

// ---------------------------------------------------------------------------
// K4: h_new = h + relu(LN(hW4 + (wacc/z)@W5.T))
// ---------------------------------------------------------------------------
__global__ __launch_bounds__(256) void k4_final(
    const float* __restrict__ wacc, const float* __restrict__ zacc,
    const float* __restrict__ W5,
    const float* __restrict__ hW4, const float* __restrict__ h,
    const float* __restrict__ ln_h_w, const float* __restrict__ ln_h_b,
    float* __restrict__ out_h)
{
    const int i = blockIdx.x;
    const int k = threadIdx.x;
    __shared__ float xs[DD];
    __shared__ float red[256];

    const float zinv = 1.f / zacc[i];
    xs[k] = wacc[(size_t)i * DD + k] * zinv;
    __syncthreads();
    float a = 0.f;
    for (int d = 0; d < DD; ++d) a = fmaf(xs[d], W5[(size_t)k * DD + d], a);
    const float p = hW4[(size_t)i * DD + k] + a;

    red[k] = p;
    __syncthreads();
    for (int s = 128; s > 0; s >>= 1) {
        if (k < s) red[k] += red[k + s];
        __syncthreads();
    }
    const float mu = red[0] * (1.f / 256.f);
    __syncthreads();
    const float d0 = p - mu;
    red[k] = d0 * d0;
    __syncthreads();
    for (int s = 128; s > 0; s >>= 1) {
        if (k < s) red[k] += red[k + s];
        __syncthreads();
    }
    const float rs = rsqrtf(red[0] * (1.f / 256.f) + 1e-5f);
    float v = d0 * rs * ln_h_w[k] + ln_h_b[k];
    v = fmaxf(v, 0.f);
    out_h[(size_t)i * DD + k] = h[(size_t)i * DD + k] + v;
}

// ---------------------------------------------------------------------------
extern "C" void kernel_launch(void* const* d_in, const int* in_sizes, int n_in,
                              void* d_out, int out_size, void* d_ws, size_t ws_size,
                              hipStream_t stream)
{
    const float* h      = (const float*)d_in[0];
    const float* e      = (const float*)d_in[1];
    const float* t_emb  = (const float*)d_in[2];
    const float* W1     = (const float*)d_in[3];
    const float* W2     = (const float*)d_in[4];
    const float* W3     = (const float*)d_in[5];
    const float* W_t    = (const float*)d_in[6];
    const float* W4     = (const float*)d_in[7];
    const float* W5     = (const float*)d_in[8];
    const float* gate_w = (const float*)d_in[9];
    const float* gate_b = (const float*)d_in[10];
    const float* ln_e_w = (const float*)d_in[11];
    const float* ln_e_b = (const float*)d_in[12];
    const float* ln_h_w = (const float*)d_in[13];
    const float* ln_h_b = (const float*)d_in[14];

    float* out_h = (float*)d_out;
    float* out_e = out_h + NN * DD;

    // workspace layout (~2.3 MiB)
    float* wsf  = (float*)d_ws;
    float* hb   = wsf;                        // 131072 (hW1 + t_bias)
    float* hW2  = hb + NN * DD;               // 131072
    float* hW4  = hW2 + NN * DD;              // 131072
    float* wacc = hW4 + NN * DD;              // 131072
    float* zacc = wacc + NN * DD;             // 512
    unsigned short* w3b = (unsigned short*)(zacc + NN);  // 65536 ushort

    k1_pre<<<66, 256, 0, stream>>>(h, W1, W2, W4, t_emb, W_t, W3,
                                   hb, hW2, hW4, w3b, wacc, zacc);
    k2_big<<<8192, 256, 0, stream>>>(e, w3b, hb, hW2, gate_w, gate_b,
                                     ln_e_w, ln_e_b, out_e, wacc, zacc);
    k4_final<<<512, 256, 0, stream>>>(wacc, zacc, W5, hW4, h,
                                      ln_h_w, ln_h_b, out_h);
}